// Round 7
// baseline (738.534 us; speedup 1.0000x reference)
//
#include <hip/hip_runtime.h>
#include <math.h>

#define N_NODES 100000
#define N_EDGES 3200000
#define NPB    128                               // nodes per bucket
#define NBUCK  ((N_NODES + NPB - 1) / NPB)       // 782
#define NBLKA  256                               // pass-A edge blocks
#define EPB    ((N_EDGES + NBLKA - 1) / NBLKA)   // 12500
#define NB_BLK ((N_NODES + 255) / 256)

// main-path ws words: dinv N + xs 16N + hbuf 16N + P E + cmat NBUCK*NBLKA
//                     + bt (NBUCK+1) + flag
#define MAIN_WS_WORDS (33u*N_NODES + N_EDGES + NBUCK*NBLKA + NBUCK + 2u)
#define MAIN_WS_BYTES (MAIN_WS_WORDS * 4u)
#define ATOMIC_WS_BYTES ((33u*N_NODES + 16u) * 4u)

// ---------------------------------------------------------------------------
__global__ void k_detect_i64(const int* __restrict__ ei_words, int* __restrict__ flag) {
    if (blockIdx.x == 0 && threadIdx.x == 0) {
        int allzero = 1;
        for (int i = 0; i < 64; i++)
            if (ei_words[2 * i + 1] != 0) allzero = 0;
        *flag = allzero;  // 1 => int64 layout
    }
}

__device__ __forceinline__ unsigned load_idx(const int* p32, const long long* p64,
                                             int is64, int e) {
    return is64 ? (unsigned)(unsigned long long)__builtin_nontemporal_load(&p64[e])
                : (unsigned)__builtin_nontemporal_load(&p32[e]);
}

// ---------------------------------------------------------------------------
// A1: per-(bucket, edge-block) counts
__global__ __launch_bounds__(256) void k_bcount(const int* __restrict__ dst32,
                                                const long long* __restrict__ dst64,
                                                const int* __restrict__ flag,
                                                int* __restrict__ cmat) {
    __shared__ int lc[NBUCK];
    int t = threadIdx.x, blk = blockIdx.x;
    for (int i = t; i < NBUCK; i += 256) lc[i] = 0;
    __syncthreads();
    int is64 = *flag;
    int e0 = blk * EPB, e1 = e0 + EPB; if (e1 > N_EDGES) e1 = N_EDGES;
    for (int e = e0 + t; e < e1; e += 256) {
        unsigned d = load_idx(dst32, dst64, is64, e);
        if (d < N_NODES) atomicAdd(&lc[d >> 7], 1);
    }
    __syncthreads();
    for (int b = t; b < NBUCK; b += 256) cmat[b * NBLKA + blk] = lc[b];
}

// A2: bucket totals
__global__ __launch_bounds__(256) void k_bsum(const int* __restrict__ cmat,
                                              int* __restrict__ bt) {
    int b = blockIdx.x, t = threadIdx.x;
    int v = cmat[b * NBLKA + t];
#pragma unroll
    for (int off = 32; off > 0; off >>= 1) v += __shfl_down(v, off, 64);
    __shared__ int s[4];
    if ((t & 63) == 0) s[t >> 6] = v;
    __syncthreads();
    if (t == 0) bt[b] = s[0] + s[1] + s[2] + s[3];
}

// A3: exclusive scan of bt[0..NBUCK); bt[NBUCK] = total
__global__ __launch_bounds__(1024) void k_btscan(int* __restrict__ bt) {
    __shared__ int s[1024];
    int t = threadIdx.x;
    s[t] = (t < NBUCK) ? bt[t] : 0;
    __syncthreads();
    for (int off = 1; off < 1024; off <<= 1) {
        int v = (t >= off) ? s[t - off] : 0;
        __syncthreads();
        s[t] += v;
        __syncthreads();
    }
    if (t < NBUCK) bt[t] = (t == 0) ? 0 : s[t - 1];
    if (t == 0) bt[NBUCK] = s[NBUCK - 1];
}

// A4: cmat row -> absolute offsets
__global__ __launch_bounds__(256) void k_boffs(int* __restrict__ cmat,
                                               const int* __restrict__ bt) {
    __shared__ int s[256];
    int b = blockIdx.x, t = threadIdx.x;
    s[t] = cmat[b * NBLKA + t];
    __syncthreads();
    for (int off = 1; off < 256; off <<= 1) {
        int v = (t >= off) ? s[t - off] : 0;
        __syncthreads();
        s[t] += v;
        __syncthreads();
    }
    cmat[b * NBLKA + t] = ((t == 0) ? 0 : s[t - 1]) + bt[b];
}

// A5: scatter packed (dstLow<<17 | src) into bucket-major P
__global__ __launch_bounds__(256) void k_bscatter(const int* __restrict__ src32,
                                                  const long long* __restrict__ src64,
                                                  const int* __restrict__ dst32,
                                                  const long long* __restrict__ dst64,
                                                  const int* __restrict__ flag,
                                                  const int* __restrict__ cmat,
                                                  int* __restrict__ P) {
    __shared__ int cur[NBUCK];
    int t = threadIdx.x, blk = blockIdx.x;
    for (int i = t; i < NBUCK; i += 256) cur[i] = cmat[i * NBLKA + blk];
    __syncthreads();
    int is64 = *flag;
    int e0 = blk * EPB, e1 = e0 + EPB; if (e1 > N_EDGES) e1 = N_EDGES;
    for (int e = e0 + t; e < e1; e += 256) {
        unsigned d = load_idx(dst32, dst64, is64, e);
        if (d < N_NODES) {
            unsigned s = load_idx(src32, src64, is64, e);
            int pos = atomicAdd(&cur[d >> 7], 1);
            P[pos] = (int)(((d & 127u) << 17) | (s & 0x1FFFFu));
        }
    }
}

// per-bucket degree histogram -> dinv
__global__ __launch_bounds__(256) void k_bdinv(const int* __restrict__ P,
                                               const int* __restrict__ bt,
                                               float* __restrict__ dinv) {
    __shared__ int cnt[NPB];
    int b = blockIdx.x, t = threadIdx.x;
    for (int i = t; i < NPB; i += 256) cnt[i] = 0;
    __syncthreads();
    int s0 = bt[b], s1 = bt[b + 1];
    for (int j = s0 + t; j < s1; j += 256)
        atomicAdd(&cnt[__builtin_nontemporal_load(&P[j]) >> 17], 1);
    __syncthreads();
    for (int i = t; i < NPB; i += 256) {
        int n = b * NPB + i;
        if (n < N_NODES) dinv[n] = rsqrtf((float)cnt[i] + 1.0f);
    }
}

// ---------------------------------------------------------------------------
// Layer-1 GEMM -> two 8-float planes: xsp[p][n][f] = dinv[n]*(h@W1)[n][p*8+f]
__global__ __launch_bounds__(256) void k_gemm1_p(const float* __restrict__ h,
                                                 const float* __restrict__ W,
                                                 const float* __restrict__ dinv,
                                                 float* __restrict__ xs) {
    __shared__ float Wt[16 * 132];
    __shared__ float Hs[16 * 132];
    int tid = threadIdx.x;
    for (int i = tid; i < 2048; i += 256) {
        int k = i >> 4, f = i & 15;
        Wt[f * 132 + k] = W[i];
    }
    int nodeBase = blockIdx.x * 16;
    for (int i = tid; i < 512; i += 256) {
        int r = i >> 5, c = i & 31;
        float4 v = ((const float4*)(h + (size_t)(nodeBase + r) * 128))[c];
        *((float4*)&Hs[r * 132 + c * 4]) = v;
    }
    __syncthreads();
    int nl = tid >> 4, f = tid & 15;
    int n = nodeBase + nl;
    const float* hr = &Hs[nl * 132];
    const float* wr = &Wt[f * 132];
    float s = 0.0f;
#pragma unroll
    for (int k = 0; k < 128; k++) s += hr[k] * wr[k];
    s *= dinv[n];
    xs[(f >> 3) * (8 * N_NODES) + n * 8 + (f & 7)] = s;
}

// small GEMM -> F0-wide plane
template <int FI, int FO>
__global__ __launch_bounds__(256) void k_gemm_smallp(const float* __restrict__ x,
                                                     const float* __restrict__ W,
                                                     const float* __restrict__ dinv,
                                                     float* __restrict__ xs) {
    int i = blockIdx.x * 256 + threadIdx.x;
    if (i >= N_NODES * FO) return;
    int n = i / FO, f = i % FO;
    float s = 0.0f;
#pragma unroll
    for (int k = 0; k < FI; k++) s += x[n * FI + k] * W[k * FO + f];
    xs[i] = s * dinv[n];
}

// ---------------------------------------------------------------------------
// Bucket-local aggregation + fused finish.
// xsp: F-wide plane; out[n*FTOT + FOFF + f] = tanh(dinv*(acc+self) + bias[f])
template <int F, int FTOT, int FOFF, int LOG>
__global__ __launch_bounds__(256) void k_agg(const int* __restrict__ P,
                                             const int* __restrict__ bt,
                                             const float* __restrict__ xsp,
                                             const float* __restrict__ dinv,
                                             const float* __restrict__ bias,
                                             float* __restrict__ out) {
    __shared__ float acc[NPB * F];
    int b = blockIdx.x, t = threadIdx.x;
    for (int i = t; i < NPB * F; i += 256) acc[i] = 0.0f;
    __syncthreads();
    int s0 = bt[b], s1 = bt[b + 1];
    int sub = t & (F - 1);
    for (int j = s0 + (t >> LOG); j < s1; j += (256 >> LOG)) {
        int ent = __builtin_nontemporal_load(&P[j]);
        int src = ent & 0x1FFFF;
        int dl  = ent >> 17;
        atomicAdd(&acc[dl * F + sub], xsp[src * F + sub]);
    }
    __syncthreads();
    for (int i = t; i < NPB * F; i += 256) {
        int n = b * NPB + (i >> LOG);
        if (n < N_NODES) {
            int fl = i & (F - 1);
            float a = acc[i] + xsp[n * F + fl];
            out[n * FTOT + FOFF + fl] = tanhf(dinv[n] * a + bias[fl]);
        }
    }
}

// Layer-3 aggregation (F=2) fused with h3 write and 2->8 classifier
__global__ __launch_bounds__(256) void k_agg_final(const int* __restrict__ P,
                                                   const int* __restrict__ bt,
                                                   const float* __restrict__ xsp,
                                                   const float* __restrict__ dinv,
                                                   const float* __restrict__ b3,
                                                   const float* __restrict__ Wc,
                                                   const float* __restrict__ bc,
                                                   float* __restrict__ out,
                                                   float* __restrict__ h3out) {
    __shared__ float acc[NPB * 2];
    __shared__ float h3s[NPB * 2];
    int b = blockIdx.x, t = threadIdx.x;
    for (int i = t; i < NPB * 2; i += 256) acc[i] = 0.0f;
    __syncthreads();
    int s0 = bt[b], s1 = bt[b + 1];
    int sub = t & 1;
    for (int j = s0 + (t >> 1); j < s1; j += 128) {
        int ent = __builtin_nontemporal_load(&P[j]);
        int src = ent & 0x1FFFF;
        int dl  = ent >> 17;
        atomicAdd(&acc[dl * 2 + sub], xsp[src * 2 + sub]);
    }
    __syncthreads();
    for (int i = t; i < NPB * 2; i += 256) {
        int n = b * NPB + (i >> 1);
        if (n < N_NODES) {
            int fl = i & 1;
            float a = tanhf(dinv[n] * (acc[i] + xsp[n * 2 + fl]) + b3[fl]);
            h3s[i] = a;
            h3out[n * 2 + fl] = a;
        }
    }
    __syncthreads();
    for (int i = t; i < NPB * 8; i += 256) {
        int ln = i >> 3, c = i & 7;
        int n = b * NPB + ln;
        if (n < N_NODES)
            out[n * 8 + c] = h3s[ln * 2] * Wc[c] + h3s[ln * 2 + 1] * Wc[8 + c] + bc[c];
    }
}

// ---------------------------------------------------------------------------
// Atomic fallback (R4 pipeline) — only if ws is unexpectedly small
__global__ __launch_bounds__(256) void k_gemm1(const float* __restrict__ h,
                                               const float* __restrict__ W,
                                               const float* __restrict__ dinv,
                                               float* __restrict__ xs, float* acc) {
    __shared__ float Wt[16 * 132];
    __shared__ float Hs[16 * 132];
    int tid = threadIdx.x;
    for (int i = tid; i < 2048; i += 256) {
        int k = i >> 4, f = i & 15;
        Wt[f * 132 + k] = W[i];
    }
    int nodeBase = blockIdx.x * 16;
    for (int i = tid; i < 512; i += 256) {
        int r = i >> 5, c = i & 31;
        float4 v = ((const float4*)(h + (size_t)(nodeBase + r) * 128))[c];
        *((float4*)&Hs[r * 132 + c * 4]) = v;
    }
    __syncthreads();
    int nl = tid >> 4, f = tid & 15;
    int n = nodeBase + nl;
    const float* hr = &Hs[nl * 132];
    const float* wr = &Wt[f * 132];
    float s = 0.0f;
#pragma unroll
    for (int k = 0; k < 128; k++) s += hr[k] * wr[k];
    s *= dinv[n];
    xs[n * 16 + f] = s;
    acc[n * 16 + f] = s;
}
template <int FI, int FO>
__global__ __launch_bounds__(256) void k_gemm_small(const float* __restrict__ x,
                                                    const float* __restrict__ W,
                                                    const float* __restrict__ dinv,
                                                    float* __restrict__ xs, float* acc) {
    int i = blockIdx.x * 256 + threadIdx.x;
    if (i >= N_NODES * FO) return;
    int n = i / FO, f = i % FO;
    float s = 0.0f;
#pragma unroll
    for (int k = 0; k < FI; k++) s += x[n * FI + k] * W[k * FO + f];
    s *= dinv[n];
    xs[i] = s;
    acc[i] = s;
}
template <int F>
__global__ __launch_bounds__(256) void k_scatter(const int* __restrict__ src32,
                                                 const long long* __restrict__ src64,
                                                 const int* __restrict__ dst32,
                                                 const long long* __restrict__ dst64,
                                                 const int* __restrict__ flag,
                                                 const float* __restrict__ xs,
                                                 float* __restrict__ acc) {
    long long gid = (long long)blockIdx.x * 256 + threadIdx.x;
    int e = (int)(gid / F), f = (int)(gid % F);
    if (e < N_EDGES) {
        int is64 = *flag;
        unsigned s = load_idx(src32, src64, is64, e);
        unsigned d = load_idx(dst32, dst64, is64, e);
        if (s < N_NODES && d < N_NODES)
            atomicAdd(&acc[d * F + f], xs[s * F + f]);
    }
}
__global__ __launch_bounds__(256) void k_deg_init(float* __restrict__ deg) {
    int i = blockIdx.x * 256 + threadIdx.x;
    if (i < N_NODES) deg[i] = 1.0f;
}
__global__ __launch_bounds__(256) void k_deg_count(const int* __restrict__ dst32,
                                                   const long long* __restrict__ dst64,
                                                   const int* __restrict__ flag,
                                                   float* __restrict__ deg) {
    int e = blockIdx.x * 256 + threadIdx.x;
    if (e < N_EDGES) {
        unsigned d = load_idx(dst32, dst64, *flag, e);
        if (d < N_NODES) atomicAdd(&deg[d], 1.0f);
    }
}
__global__ __launch_bounds__(256) void k_rsqrt(float* __restrict__ deg) {
    int i = blockIdx.x * 256 + threadIdx.x;
    if (i < N_NODES) deg[i] = rsqrtf(deg[i]);
}
template <int F>
__global__ __launch_bounds__(256) void k_finish(const float* __restrict__ acc,
                                                const float* __restrict__ dinv,
                                                const float* __restrict__ b,
                                                float* __restrict__ out) {
    int i = blockIdx.x * 256 + threadIdx.x;
    if (i >= N_NODES * F) return;
    int n = i / F, f = i % F;
    out[i] = tanhf(dinv[n] * acc[i] + b[f]);
}
__global__ __launch_bounds__(256) void k_final(const float* __restrict__ acc3,
                                               const float* __restrict__ dinv,
                                               const float* __restrict__ b3,
                                               const float* __restrict__ Wc,
                                               const float* __restrict__ bc,
                                               float* __restrict__ out,
                                               float* __restrict__ h3out) {
    int n = blockIdx.x * 256 + threadIdx.x;
    if (n >= N_NODES) return;
    float di = dinv[n];
    float a0 = tanhf(di * acc3[2 * n + 0] + b3[0]);
    float a1 = tanhf(di * acc3[2 * n + 1] + b3[1]);
    h3out[2 * n + 0] = a0;
    h3out[2 * n + 1] = a1;
#pragma unroll
    for (int c = 0; c < 8; c++)
        out[8 * n + c] = a0 * Wc[c] + a1 * Wc[8 + c] + bc[c];
}
__global__ __launch_bounds__(256) void k_zero_out(float* __restrict__ out, int n) {
    int i = blockIdx.x * 256 + threadIdx.x;
    if (i < n) out[i] = 0.0f;
}

// ---------------------------------------------------------------------------
extern "C" void kernel_launch(void* const* d_in, const int* in_sizes, int n_in,
                              void* d_out, int out_size, void* d_ws, size_t ws_size,
                              hipStream_t stream) {
    float* out = (float*)d_out;
    const float* h   = (const float*)d_in[0];
    const void*  ei  = d_in[1];
    const float* W1  = (const float*)d_in[2];
    const float* b1  = (const float*)d_in[3];
    const float* W2  = (const float*)d_in[4];
    const float* b2  = (const float*)d_in[5];
    const float* W3  = (const float*)d_in[6];
    const float* b3  = (const float*)d_in[7];
    const float* Wc  = (const float*)d_in[8];
    const float* bc  = (const float*)d_in[9];

    const int*       src32 = (const int*)ei;
    const int*       dst32 = src32 + N_EDGES;
    const long long* src64 = (const long long*)ei;
    const long long* dst64 = src64 + N_EDGES;

    float* h3out = out + 8 * N_NODES;
    const int NB_E = (N_EDGES + 255) / 256;

    if (d_ws != nullptr && ws_size >= MAIN_WS_BYTES) {
        // ------------- bucket-accumulate path -------------
        float* dinv = (float*)d_ws;                  // N
        float* xs   = dinv + N_NODES;                // 16N (planes)
        float* hbuf = xs + 16 * N_NODES;             // 16N
        int*   P    = (int*)(hbuf + 16 * N_NODES);   // E
        int*   cmat = P + N_EDGES;                   // NBUCK*NBLKA
        int*   bt   = cmat + NBUCK * NBLKA;          // NBUCK+1
        int*   flag = bt + NBUCK + 1;                // 1

        k_detect_i64<<<1, 64, 0, stream>>>(src32, flag);
        k_bcount<<<NBLKA, 256, 0, stream>>>(dst32, dst64, flag, cmat);
        k_bsum<<<NBUCK, 256, 0, stream>>>(cmat, bt);
        k_btscan<<<1, 1024, 0, stream>>>(bt);
        k_boffs<<<NBUCK, 256, 0, stream>>>(cmat, bt);
        k_bscatter<<<NBLKA, 256, 0, stream>>>(src32, src64, dst32, dst64, flag, cmat, P);
        k_bdinv<<<NBUCK, 256, 0, stream>>>(P, bt, dinv);

        // layer 1: 128 -> 16, two 8-feature planes
        k_gemm1_p<<<N_NODES / 16, 256, 0, stream>>>(h, W1, dinv, xs);
        k_agg<8, 16, 0, 3><<<NBUCK, 256, 0, stream>>>(P, bt, xs, dinv, b1, hbuf);
        k_agg<8, 16, 8, 3><<<NBUCK, 256, 0, stream>>>(P, bt, xs + 8 * N_NODES, dinv, b1 + 8, hbuf);
        // layer 2: 16 -> 4
        k_gemm_smallp<16, 4><<<(N_NODES * 4 + 255) / 256, 256, 0, stream>>>(hbuf, W2, dinv, xs);
        k_agg<4, 4, 0, 2><<<NBUCK, 256, 0, stream>>>(P, bt, xs, dinv, b2, hbuf);
        // layer 3: 4 -> 2, fused classifier
        k_gemm_smallp<4, 2><<<(N_NODES * 2 + 255) / 256, 256, 0, stream>>>(hbuf, W3, dinv, xs);
        k_agg_final<<<NBUCK, 256, 0, stream>>>(P, bt, xs, dinv, b3, Wc, bc, out, h3out);
        return;
    }

    if (d_ws != nullptr && ws_size >= ATOMIC_WS_BYTES) {
        // ------------- atomic fallback (R4) -------------
        float* ws   = (float*)d_ws;
        float* dinv = ws;
        float* bufA = dinv + N_NODES;
        float* bufB = bufA + 16 * N_NODES;
        int*   flag = (int*)(bufB + 16 * N_NODES);
        float* xs1 = bufA, *acc1 = bufB, *h1 = bufA;
        float* xs2 = bufB, *acc2 = bufB + 4 * N_NODES, *h2 = bufA;
        float* xs3 = bufB, *acc3 = bufB + 2 * N_NODES;

        k_detect_i64<<<1, 64, 0, stream>>>(src32, flag);
        k_deg_init<<<NB_BLK, 256, 0, stream>>>(dinv);
        k_deg_count<<<NB_E, 256, 0, stream>>>(dst32, dst64, flag, dinv);
        k_rsqrt<<<NB_BLK, 256, 0, stream>>>(dinv);
        k_gemm1<<<N_NODES / 16, 256, 0, stream>>>(h, W1, dinv, xs1, acc1);
        k_scatter<16><<<(int)(((long long)N_EDGES * 16 + 255) / 256), 256, 0, stream>>>(
            src32, src64, dst32, dst64, flag, xs1, acc1);
        k_finish<16><<<(N_NODES * 16 + 255) / 256, 256, 0, stream>>>(acc1, dinv, b1, h1);
        k_gemm_small<16, 4><<<(N_NODES * 4 + 255) / 256, 256, 0, stream>>>(h1, W2, dinv, xs2, acc2);
        k_scatter<4><<<(int)(((long long)N_EDGES * 4 + 255) / 256), 256, 0, stream>>>(
            src32, src64, dst32, dst64, flag, xs2, acc2);
        k_finish<4><<<(N_NODES * 4 + 255) / 256, 256, 0, stream>>>(acc2, dinv, b2, h2);
        k_gemm_small<4, 2><<<(N_NODES * 2 + 255) / 256, 256, 0, stream>>>(h2, W3, dinv, xs3, acc3);
        k_scatter<2><<<(int)(((long long)N_EDGES * 2 + 255) / 256), 256, 0, stream>>>(
            src32, src64, dst32, dst64, flag, xs3, acc3);
        k_final<<<NB_BLK, 256, 0, stream>>>(acc3, dinv, b3, Wc, bc, out, h3out);
        return;
    }

    k_zero_out<<<(out_size + 255) / 256, 256, 0, stream>>>(out, out_size);
}

// Round 10
// 435.605 us; speedup vs baseline: 1.6954x; 1.6954x over previous
//
#include <hip/hip_runtime.h>
#include <math.h>

#define N_NODES 100000
#define N_EDGES 3200000
#define NPB    256                               // nodes per bucket
#define NBUCK  ((N_NODES + NPB - 1) / NPB)       // 391
#define NBLKA  512                               // pass-A edge blocks
#define EPB    ((N_EDGES + NBLKA - 1) / NBLKA)   // 6250
#define NB_BLK ((N_NODES + 255) / 256)

// clang ext-vector for nontemporal float4 loads (HIP float4 is a struct and
// is rejected by __builtin_nontemporal_load)
typedef float f4nt __attribute__((ext_vector_type(4)));

// ws words: dinv N + rowstart N + rowend N + adj E + S max(32N,E)
//           + cmat NBUCK*NBLKA + bt (NBUCK+1) + flag
#define MAIN_WS_WORDS (3u*N_NODES + N_EDGES + 3200000u + NBUCK*NBLKA + NBUCK + 2u)
#define MAIN_WS_BYTES (MAIN_WS_WORDS * 4u)
#define ATOMIC_WS_BYTES ((33u*N_NODES + 16u) * 4u)

// ---------------------------------------------------------------------------
__global__ void k_detect_i64(const int* __restrict__ ei_words, int* __restrict__ flag) {
    if (blockIdx.x == 0 && threadIdx.x == 0) {
        int allzero = 1;
        for (int i = 0; i < 64; i++)
            if (ei_words[2 * i + 1] != 0) allzero = 0;
        *flag = allzero;  // 1 => int64 layout
    }
}

__device__ __forceinline__ unsigned load_idx(const int* p32, const long long* p64,
                                             int is64, int e) {
    return is64 ? (unsigned)(unsigned long long)__builtin_nontemporal_load(&p64[e])
                : (unsigned)__builtin_nontemporal_load(&p32[e]);
}

// ---------------------------------------------------------------------------
// A1: per-(bucket, edge-block) counts
__global__ __launch_bounds__(256) void k_bcount(const int* __restrict__ dst32,
                                                const long long* __restrict__ dst64,
                                                const int* __restrict__ flag,
                                                int* __restrict__ cmat) {
    __shared__ int lc[NBUCK];
    int t = threadIdx.x, blk = blockIdx.x;
    for (int i = t; i < NBUCK; i += 256) lc[i] = 0;
    __syncthreads();
    int is64 = *flag;
    int e0 = blk * EPB, e1 = e0 + EPB; if (e1 > N_EDGES) e1 = N_EDGES;
    for (int e = e0 + t; e < e1; e += 256) {
        unsigned d = load_idx(dst32, dst64, is64, e);
        if (d < N_NODES) atomicAdd(&lc[d >> 8], 1);
    }
    __syncthreads();
    for (int b = t; b < NBUCK; b += 256) cmat[b * NBLKA + blk] = lc[b];
}

// A2: bucket totals (NBLKA=512, 256 threads sum 2 each)
__global__ __launch_bounds__(256) void k_bsum(const int* __restrict__ cmat,
                                              int* __restrict__ bt) {
    int b = blockIdx.x, t = threadIdx.x;
    int v = cmat[b * NBLKA + t] + cmat[b * NBLKA + t + 256];
#pragma unroll
    for (int off = 32; off > 0; off >>= 1) v += __shfl_down(v, off, 64);
    __shared__ int s[4];
    if ((t & 63) == 0) s[t >> 6] = v;
    __syncthreads();
    if (t == 0) bt[b] = s[0] + s[1] + s[2] + s[3];
}

// A3: exclusive scan of bt[0..NBUCK); bt[NBUCK] = total
__global__ __launch_bounds__(512) void k_btscan(int* __restrict__ bt) {
    __shared__ int s[512];
    int t = threadIdx.x;
    s[t] = (t < NBUCK) ? bt[t] : 0;
    __syncthreads();
    for (int off = 1; off < 512; off <<= 1) {
        int v = (t >= off) ? s[t - off] : 0;
        __syncthreads();
        s[t] += v;
        __syncthreads();
    }
    if (t < NBUCK) bt[t] = (t == 0) ? 0 : s[t - 1];
    if (t == 0) bt[NBUCK] = s[NBUCK - 1];
}

// A4: cmat row -> absolute offsets (512-wide scan)
__global__ __launch_bounds__(512) void k_boffs(int* __restrict__ cmat,
                                               const int* __restrict__ bt) {
    __shared__ int s[512];
    int b = blockIdx.x, t = threadIdx.x;
    s[t] = cmat[b * NBLKA + t];
    __syncthreads();
    for (int off = 1; off < 512; off <<= 1) {
        int v = (t >= off) ? s[t - off] : 0;
        __syncthreads();
        s[t] += v;
        __syncthreads();
    }
    cmat[b * NBLKA + t] = ((t == 0) ? 0 : s[t - 1]) + bt[b];
}

// A5: scatter packed (dstLow<<17 | src) into bucket-major P
__global__ __launch_bounds__(256) void k_bscatter(const int* __restrict__ src32,
                                                  const long long* __restrict__ src64,
                                                  const int* __restrict__ dst32,
                                                  const long long* __restrict__ dst64,
                                                  const int* __restrict__ flag,
                                                  const int* __restrict__ cmat,
                                                  int* __restrict__ P) {
    __shared__ int cur[NBUCK];
    int t = threadIdx.x, blk = blockIdx.x;
    for (int i = t; i < NBUCK; i += 256) cur[i] = cmat[i * NBLKA + blk];
    __syncthreads();
    int is64 = *flag;
    int e0 = blk * EPB, e1 = e0 + EPB; if (e1 > N_EDGES) e1 = N_EDGES;
    for (int e = e0 + t; e < e1; e += 256) {
        unsigned d = load_idx(dst32, dst64, is64, e);
        if (d < N_NODES) {
            unsigned s = load_idx(src32, src64, is64, e);
            int pos = atomicAdd(&cur[d >> 8], 1);
            P[pos] = (int)(((d & 255u) << 17) | (s & 0x1FFFFu));
        }
    }
}

// B: per-bucket counting sort -> adj, rowstart, rowend, dinv
__global__ __launch_bounds__(256) void k_bbuild(const int* __restrict__ P,
                                                const int* __restrict__ bt,
                                                int* __restrict__ adj,
                                                int* __restrict__ rowstart,
                                                int* __restrict__ rowend,
                                                float* __restrict__ dinv) {
    __shared__ int cnt[NPB];
    __shared__ int s[NPB];
    int b = blockIdx.x, t = threadIdx.x;
    int bo = bt[b], be = bt[b + 1];
    cnt[t] = 0;
    __syncthreads();
    for (int i = bo + t; i < be; i += 256)
        atomicAdd(&cnt[__builtin_nontemporal_load(&P[i]) >> 17], 1);
    __syncthreads();
    s[t] = cnt[t];
    __syncthreads();
    for (int off = 1; off < 256; off <<= 1) {
        int v = (t >= off) ? s[t - off] : 0;
        __syncthreads();
        s[t] += v;
        __syncthreads();
    }
    int ex = (t == 0) ? 0 : s[t - 1];
    int node = b * NPB + t;
    if (node < N_NODES) {
        rowstart[node] = bo + ex;
        rowend[node]   = bo + ex + cnt[t];
        dinv[node]     = rsqrtf((float)cnt[t] + 1.0f);
    }
    __syncthreads();
    s[t] = ex;  // cursors
    __syncthreads();
    for (int i = bo + t; i < be; i += 256) {
        int ent = __builtin_nontemporal_load(&P[i]);
        int pos = bo + atomicAdd(&s[ent >> 17], 1);
        adj[pos] = ent & 0x1FFFF;
    }
}

// ---------------------------------------------------------------------------
// Layer-1 GEMM -> two 8-float planes: xs[p][n][f] = dinv[n]*(h@W1)[n][p*8+f]
__global__ __launch_bounds__(256) void k_gemm1_p(const float* __restrict__ h,
                                                 const float* __restrict__ W,
                                                 const float* __restrict__ dinv,
                                                 float* __restrict__ xs) {
    __shared__ float Wt[16 * 132];
    __shared__ float Hs[16 * 132];
    int tid = threadIdx.x;
    for (int i = tid; i < 2048; i += 256) {
        int k = i >> 4, f = i & 15;
        Wt[f * 132 + k] = W[i];
    }
    int nodeBase = blockIdx.x * 16;
    for (int i = tid; i < 512; i += 256) {
        int r = i >> 5, c = i & 31;
        f4nt v = __builtin_nontemporal_load(
            ((const f4nt*)(h + (size_t)(nodeBase + r) * 128)) + c);
        *((f4nt*)&Hs[r * 132 + c * 4]) = v;
    }
    __syncthreads();
    int nl = tid >> 4, f = tid & 15;
    int n = nodeBase + nl;
    const float* hr = &Hs[nl * 132];
    const float* wr = &Wt[f * 132];
    float s = 0.0f;
#pragma unroll
    for (int k = 0; k < 128; k++) s += hr[k] * wr[k];
    s *= dinv[n];
    xs[(f >> 3) * (8 * N_NODES) + n * 8 + (f & 7)] = s;
}

// small GEMM -> FO-wide plane (pre-scaled by dinv)
template <int FI, int FO>
__global__ __launch_bounds__(256) void k_gemm_smallp(const float* __restrict__ x,
                                                     const float* __restrict__ W,
                                                     const float* __restrict__ dinv,
                                                     float* __restrict__ xs) {
    int i = blockIdx.x * 256 + threadIdx.x;
    if (i >= N_NODES * FO) return;
    int n = i / FO, f = i % FO;
    float s = 0.0f;
#pragma unroll
    for (int k = 0; k < FI; k++) s += x[n * FI + k] * W[k * FO + f];
    xs[i] = s * dinv[n];
}

// ---------------------------------------------------------------------------
// CSR pull + fused finish. NL lanes/node, R=NL/F neighbor slots.
// out[n*FTOT + FOFF + f] = tanh(dinv[n]*(sum + self) + bias[f])
template <int F, int NL, int FTOT, int FOFF>
__global__ __launch_bounds__(256) void k_pull(const float* __restrict__ xsp,
                                              const int* __restrict__ adj,
                                              const int* __restrict__ rowstart,
                                              const int* __restrict__ rowend,
                                              const float* __restrict__ dinv,
                                              const float* __restrict__ bias,
                                              float* __restrict__ out) {
    constexpr int R = NL / F;
    int t = threadIdx.x;
    int g = t / NL, q = t % NL;
    int f = q % F, k = q / F;
    int n = blockIdx.x * (256 / NL) + g;
    if (n >= N_NODES) return;
    int s0 = rowstart[n], e0 = rowend[n];
    float acc = 0.0f;
    for (int j = s0 + k; j < e0; j += R)
        acc += xsp[__builtin_nontemporal_load(&adj[j]) * F + f];
#pragma unroll
    for (int off = NL / 2; off >= F; off >>= 1)
        acc += __shfl_xor(acc, off, 64);
    if (k == 0) {
        acc += xsp[n * F + f];  // self loop
        out[n * FTOT + FOFF + f] = tanhf(dinv[n] * acc + bias[f]);
    }
}

// Layer-3 pull (F=2, NL=8, R=4) fused with h3 write and 2->8 classifier.
__global__ __launch_bounds__(256) void k_pull_final(const float* __restrict__ xsp,
                                                    const int* __restrict__ adj,
                                                    const int* __restrict__ rowstart,
                                                    const int* __restrict__ rowend,
                                                    const float* __restrict__ dinv,
                                                    const float* __restrict__ b3,
                                                    const float* __restrict__ Wc,
                                                    const float* __restrict__ bc,
                                                    float* __restrict__ out,
                                                    float* __restrict__ h3out) {
    const int NL = 8;
    int t = threadIdx.x;
    int g = t / NL, q = t % NL;
    int f = q & 1, k = q >> 1;
    int n = blockIdx.x * (256 / NL) + g;
    if (n >= N_NODES) return;
    int s0 = rowstart[n], e0 = rowend[n];
    float acc = 0.0f;
    for (int j = s0 + k; j < e0; j += 4)
        acc += xsp[__builtin_nontemporal_load(&adj[j]) * 2 + f];
    acc += __shfl_xor(acc, 4, 64);
    acc += __shfl_xor(acc, 2, 64);
    float a = 0.0f;
    if (q < 2) {
        acc += xsp[n * 2 + f];
        a = tanhf(dinv[n] * acc + b3[f]);
        h3out[2 * n + f] = a;
    }
    int wl = t & 63, gb = wl & ~7;
    float a0 = __shfl(a, gb, 64);
    float a1 = __shfl(a, gb + 1, 64);
    out[8 * n + q] = a0 * Wc[q] + a1 * Wc[8 + q] + bc[q];
}

// ---------------------------------------------------------------------------
// Atomic fallback (R4 pipeline) — only if ws is unexpectedly small
__global__ __launch_bounds__(256) void k_gemm1(const float* __restrict__ h,
                                               const float* __restrict__ W,
                                               const float* __restrict__ dinv,
                                               float* __restrict__ xs, float* acc) {
    __shared__ float Wt[16 * 132];
    __shared__ float Hs[16 * 132];
    int tid = threadIdx.x;
    for (int i = tid; i < 2048; i += 256) {
        int k = i >> 4, f = i & 15;
        Wt[f * 132 + k] = W[i];
    }
    int nodeBase = blockIdx.x * 16;
    for (int i = tid; i < 512; i += 256) {
        int r = i >> 5, c = i & 31;
        float4 v = ((const float4*)(h + (size_t)(nodeBase + r) * 128))[c];
        *((float4*)&Hs[r * 132 + c * 4]) = v;
    }
    __syncthreads();
    int nl = tid >> 4, f = tid & 15;
    int n = nodeBase + nl;
    const float* hr = &Hs[nl * 132];
    const float* wr = &Wt[f * 132];
    float s = 0.0f;
#pragma unroll
    for (int k = 0; k < 128; k++) s += hr[k] * wr[k];
    s *= dinv[n];
    xs[n * 16 + f] = s;
    acc[n * 16 + f] = s;
}
template <int FI, int FO>
__global__ __launch_bounds__(256) void k_gemm_small(const float* __restrict__ x,
                                                    const float* __restrict__ W,
                                                    const float* __restrict__ dinv,
                                                    float* __restrict__ xs, float* acc) {
    int i = blockIdx.x * 256 + threadIdx.x;
    if (i >= N_NODES * FO) return;
    int n = i / FO, f = i % FO;
    float s = 0.0f;
#pragma unroll
    for (int k = 0; k < FI; k++) s += x[n * FI + k] * W[k * FO + f];
    s *= dinv[n];
    xs[i] = s;
    acc[i] = s;
}
template <int F>
__global__ __launch_bounds__(256) void k_scatter(const int* __restrict__ src32,
                                                 const long long* __restrict__ src64,
                                                 const int* __restrict__ dst32,
                                                 const long long* __restrict__ dst64,
                                                 const int* __restrict__ flag,
                                                 const float* __restrict__ xs,
                                                 float* __restrict__ acc) {
    long long gid = (long long)blockIdx.x * 256 + threadIdx.x;
    int e = (int)(gid / F), f = (int)(gid % F);
    if (e < N_EDGES) {
        int is64 = *flag;
        unsigned s = load_idx(src32, src64, is64, e);
        unsigned d = load_idx(dst32, dst64, is64, e);
        if (s < N_NODES && d < N_NODES)
            atomicAdd(&acc[d * F + f], xs[s * F + f]);
    }
}
__global__ __launch_bounds__(256) void k_deg_init(float* __restrict__ deg) {
    int i = blockIdx.x * 256 + threadIdx.x;
    if (i < N_NODES) deg[i] = 1.0f;
}
__global__ __launch_bounds__(256) void k_deg_count(const int* __restrict__ dst32,
                                                   const long long* __restrict__ dst64,
                                                   const int* __restrict__ flag,
                                                   float* __restrict__ deg) {
    int e = blockIdx.x * 256 + threadIdx.x;
    if (e < N_EDGES) {
        unsigned d = load_idx(dst32, dst64, *flag, e);
        if (d < N_NODES) atomicAdd(&deg[d], 1.0f);
    }
}
__global__ __launch_bounds__(256) void k_rsqrt(float* __restrict__ deg) {
    int i = blockIdx.x * 256 + threadIdx.x;
    if (i < N_NODES) deg[i] = rsqrtf(deg[i]);
}
template <int F>
__global__ __launch_bounds__(256) void k_finish(const float* __restrict__ acc,
                                                const float* __restrict__ dinv,
                                                const float* __restrict__ b,
                                                float* __restrict__ out) {
    int i = blockIdx.x * 256 + threadIdx.x;
    if (i >= N_NODES * F) return;
    int n = i / F, f = i % F;
    out[i] = tanhf(dinv[n] * acc[i] + b[f]);
}
__global__ __launch_bounds__(256) void k_final(const float* __restrict__ acc3,
                                               const float* __restrict__ dinv,
                                               const float* __restrict__ b3,
                                               const float* __restrict__ Wc,
                                               const float* __restrict__ bc,
                                               float* __restrict__ out,
                                               float* __restrict__ h3out) {
    int n = blockIdx.x * 256 + threadIdx.x;
    if (n >= N_NODES) return;
    float di = dinv[n];
    float a0 = tanhf(di * acc3[2 * n + 0] + b3[0]);
    float a1 = tanhf(di * acc3[2 * n + 1] + b3[1]);
    h3out[2 * n + 0] = a0;
    h3out[2 * n + 1] = a1;
#pragma unroll
    for (int c = 0; c < 8; c++)
        out[8 * n + c] = a0 * Wc[c] + a1 * Wc[8 + c] + bc[c];
}
__global__ __launch_bounds__(256) void k_zero_out(float* __restrict__ out, int n) {
    int i = blockIdx.x * 256 + threadIdx.x;
    if (i < n) out[i] = 0.0f;
}

// ---------------------------------------------------------------------------
extern "C" void kernel_launch(void* const* d_in, const int* in_sizes, int n_in,
                              void* d_out, int out_size, void* d_ws, size_t ws_size,
                              hipStream_t stream) {
    float* out = (float*)d_out;
    const float* h   = (const float*)d_in[0];
    const void*  ei  = d_in[1];
    const float* W1  = (const float*)d_in[2];
    const float* b1  = (const float*)d_in[3];
    const float* W2  = (const float*)d_in[4];
    const float* b2  = (const float*)d_in[5];
    const float* W3  = (const float*)d_in[6];
    const float* b3  = (const float*)d_in[7];
    const float* Wc  = (const float*)d_in[8];
    const float* bc  = (const float*)d_in[9];

    const int*       src32 = (const int*)ei;
    const int*       dst32 = src32 + N_EDGES;
    const long long* src64 = (const long long*)ei;
    const long long* dst64 = src64 + N_EDGES;

    float* h3out = out + 8 * N_NODES;
    const int NB_E = (N_EDGES + 255) / 256;

    if (d_ws != nullptr && ws_size >= MAIN_WS_BYTES) {
        // ------------- multisplit CSR + plane-pull path -------------
        float* dinv   = (float*)d_ws;                // N
        int* rowstart = (int*)(dinv + N_NODES);      // N
        int* rowend   = rowstart + N_NODES;          // N
        int* adj      = rowend + N_NODES;            // E
        int* S        = adj + N_EDGES;               // max(32N, E)
        float* xs     = (float*)S;                   // 16N (after build)
        float* hbuf   = xs + 16 * N_NODES;           // 16N
        int* P        = S;                           // E (during build)
        int* cmat     = S + 3200000;                 // NBUCK*NBLKA
        int* bt       = cmat + NBUCK * NBLKA;        // NBUCK+1
        int* flag     = bt + NBUCK + 1;              // 1

        k_detect_i64<<<1, 64, 0, stream>>>(src32, flag);
        k_bcount<<<NBLKA, 256, 0, stream>>>(dst32, dst64, flag, cmat);
        k_bsum<<<NBUCK, 256, 0, stream>>>(cmat, bt);
        k_btscan<<<1, 512, 0, stream>>>(bt);
        k_boffs<<<NBUCK, 512, 0, stream>>>(cmat, bt);
        k_bscatter<<<NBLKA, 256, 0, stream>>>(src32, src64, dst32, dst64, flag, cmat, P);
        k_bbuild<<<NBUCK, 256, 0, stream>>>(P, bt, adj, rowstart, rowend, dinv);

        // layer 1: 128 -> 16 via two 8-wide planes (each 3.2 MB, L2-resident)
        k_gemm1_p<<<N_NODES / 16, 256, 0, stream>>>(h, W1, dinv, xs);
        k_pull<8, 64, 16, 0><<<25000, 256, 0, stream>>>(
            xs, adj, rowstart, rowend, dinv, b1, hbuf);
        k_pull<8, 64, 16, 8><<<25000, 256, 0, stream>>>(
            xs + 8 * N_NODES, adj, rowstart, rowend, dinv, b1 + 8, hbuf);
        // layer 2: 16 -> 4
        k_gemm_smallp<16, 4><<<(N_NODES * 4 + 255) / 256, 256, 0, stream>>>(hbuf, W2, dinv, xs);
        k_pull<4, 32, 4, 0><<<12500, 256, 0, stream>>>(
            xs, adj, rowstart, rowend, dinv, b2, hbuf);
        // layer 3: 4 -> 2, fused classifier
        k_gemm_smallp<4, 2><<<(N_NODES * 2 + 255) / 256, 256, 0, stream>>>(hbuf, W3, dinv, xs);
        k_pull_final<<<3125, 256, 0, stream>>>(
            xs, adj, rowstart, rowend, dinv, b3, Wc, bc, out, h3out);
        return;
    }

    if (d_ws != nullptr && ws_size >= ATOMIC_WS_BYTES) {
        // ------------- atomic fallback (R4) -------------
        float* ws   = (float*)d_ws;
        float* dinv = ws;
        float* bufA = dinv + N_NODES;
        float* bufB = bufA + 16 * N_NODES;
        int*   flag = (int*)(bufB + 16 * N_NODES);
        float* xs1 = bufA, *acc1 = bufB, *h1 = bufA;
        float* xs2 = bufB, *acc2 = bufB + 4 * N_NODES, *h2 = bufA;
        float* xs3 = bufB, *acc3 = bufB + 2 * N_NODES;

        k_detect_i64<<<1, 64, 0, stream>>>(src32, flag);
        k_deg_init<<<NB_BLK, 256, 0, stream>>>(dinv);
        k_deg_count<<<NB_E, 256, 0, stream>>>(dst32, dst64, flag, dinv);
        k_rsqrt<<<NB_BLK, 256, 0, stream>>>(dinv);
        k_gemm1<<<N_NODES / 16, 256, 0, stream>>>(h, W1, dinv, xs1, acc1);
        k_scatter<16><<<(int)(((long long)N_EDGES * 16 + 255) / 256), 256, 0, stream>>>(
            src32, src64, dst32, dst64, flag, xs1, acc1);
        k_finish<16><<<(N_NODES * 16 + 255) / 256, 256, 0, stream>>>(acc1, dinv, b1, h1);
        k_gemm_small<16, 4><<<(N_NODES * 4 + 255) / 256, 256, 0, stream>>>(h1, W2, dinv, xs2, acc2);
        k_scatter<4><<<(int)(((long long)N_EDGES * 4 + 255) / 256), 256, 0, stream>>>(
            src32, src64, dst32, dst64, flag, xs2, acc2);
        k_finish<4><<<(N_NODES * 4 + 255) / 256, 256, 0, stream>>>(acc2, dinv, b2, h2);
        k_gemm_small<4, 2><<<(N_NODES * 2 + 255) / 256, 256, 0, stream>>>(h2, W3, dinv, xs3, acc3);
        k_scatter<2><<<(int)(((long long)N_EDGES * 2 + 255) / 256), 256, 0, stream>>>(
            src32, src64, dst32, dst64, flag, xs3, acc3);
        k_final<<<NB_BLK, 256, 0, stream>>>(acc3, dinv, b3, Wc, bc, out, h3out);
        return;
    }

    k_zero_out<<<(out_size + 255) / 256, 256, 0, stream>>>(out, out_size);
}

// Round 11
// 388.161 us; speedup vs baseline: 1.9026x; 1.1222x over previous
//
#include <hip/hip_runtime.h>
#include <math.h>

#define N_NODES 100000
#define N_EDGES 3200000
#define NPB    256                               // nodes per bucket
#define NBUCK  ((N_NODES + NPB - 1) / NPB)       // 391
#define NBLKA  512                               // pass-A edge blocks
#define EPB    ((N_EDGES + NBLKA - 1) / NBLKA)   // 6250
#define NB_BLK ((N_NODES + 255) / 256)

// clang ext-vector for nontemporal float4 loads (HIP float4 is a struct and
// is rejected by __builtin_nontemporal_load)
typedef float f4nt __attribute__((ext_vector_type(4)));

// ws words: dinv N + rowstart N + rowend N + adj E + S max(32N,E)
//           + cmat NBUCK*NBLKA + bt (NBUCK+1) + flag
#define MAIN_WS_WORDS (3u*N_NODES + N_EDGES + 3200000u + NBUCK*NBLKA + NBUCK + 2u)
#define MAIN_WS_BYTES (MAIN_WS_WORDS * 4u)
#define ATOMIC_WS_BYTES ((33u*N_NODES + 16u) * 4u)

// ---------------------------------------------------------------------------
// per-wave edge-dtype probe: int64 LE values < 1e5 have all odd words zero.
// Must be called with all 64 lanes of each wave active (kernel top).
__device__ __forceinline__ int detect_is64(const int* __restrict__ w) {
    int t = threadIdx.x & 63;
    int v = w[2 * t + 1];
    unsigned long long nz = __ballot(v != 0);
    return nz == 0ull;
}

__global__ void k_detect_i64(const int* __restrict__ ei_words, int* __restrict__ flag) {
    if (blockIdx.x == 0 && threadIdx.x == 0) {
        int allzero = 1;
        for (int i = 0; i < 64; i++)
            if (ei_words[2 * i + 1] != 0) allzero = 0;
        *flag = allzero;  // 1 => int64 layout
    }
}

__device__ __forceinline__ unsigned load_idx(const int* p32, const long long* p64,
                                             int is64, int e) {
    return is64 ? (unsigned)(unsigned long long)__builtin_nontemporal_load(&p64[e])
                : (unsigned)__builtin_nontemporal_load(&p32[e]);
}

// ---------------------------------------------------------------------------
// A1: per-(bucket, edge-block) counts
__global__ __launch_bounds__(256) void k_bcount(const int* __restrict__ dst32,
                                                const long long* __restrict__ dst64,
                                                int* __restrict__ cmat) {
    int is64 = detect_is64(dst32 - 2 * N_EDGES);  // probe src words (start of ei)
    __shared__ int lc[NBUCK];
    int t = threadIdx.x, blk = blockIdx.x;
    for (int i = t; i < NBUCK; i += 256) lc[i] = 0;
    __syncthreads();
    int e0 = blk * EPB, e1 = e0 + EPB; if (e1 > N_EDGES) e1 = N_EDGES;
    for (int e = e0 + t; e < e1; e += 256) {
        unsigned d = load_idx(dst32, dst64, is64, e);
        if (d < N_NODES) atomicAdd(&lc[d >> 8], 1);
    }
    __syncthreads();
    for (int b = t; b < NBUCK; b += 256) cmat[b * NBLKA + blk] = lc[b];
}

// A2: bucket totals (NBLKA=512, 256 threads sum 2 each)
__global__ __launch_bounds__(256) void k_bsum(const int* __restrict__ cmat,
                                              int* __restrict__ bt) {
    int b = blockIdx.x, t = threadIdx.x;
    int v = cmat[b * NBLKA + t] + cmat[b * NBLKA + t + 256];
#pragma unroll
    for (int off = 32; off > 0; off >>= 1) v += __shfl_down(v, off, 64);
    __shared__ int s[4];
    if ((t & 63) == 0) s[t >> 6] = v;
    __syncthreads();
    if (t == 0) bt[b] = s[0] + s[1] + s[2] + s[3];
}

// A3: exclusive scan of bt[0..NBUCK); bt[NBUCK] = total
__global__ __launch_bounds__(512) void k_btscan(int* __restrict__ bt) {
    __shared__ int s[512];
    int t = threadIdx.x;
    s[t] = (t < NBUCK) ? bt[t] : 0;
    __syncthreads();
    for (int off = 1; off < 512; off <<= 1) {
        int v = (t >= off) ? s[t - off] : 0;
        __syncthreads();
        s[t] += v;
        __syncthreads();
    }
    if (t < NBUCK) bt[t] = (t == 0) ? 0 : s[t - 1];
    if (t == 0) bt[NBUCK] = s[NBUCK - 1];
}

// A4: cmat row -> absolute offsets (512-wide scan)
__global__ __launch_bounds__(512) void k_boffs(int* __restrict__ cmat,
                                               const int* __restrict__ bt) {
    __shared__ int s[512];
    int b = blockIdx.x, t = threadIdx.x;
    s[t] = cmat[b * NBLKA + t];
    __syncthreads();
    for (int off = 1; off < 512; off <<= 1) {
        int v = (t >= off) ? s[t - off] : 0;
        __syncthreads();
        s[t] += v;
        __syncthreads();
    }
    cmat[b * NBLKA + t] = ((t == 0) ? 0 : s[t - 1]) + bt[b];
}

// A5: scatter packed (dstLow<<17 | src) into bucket-major P
__global__ __launch_bounds__(256) void k_bscatter(const int* __restrict__ src32,
                                                  const long long* __restrict__ src64,
                                                  const int* __restrict__ dst32,
                                                  const long long* __restrict__ dst64,
                                                  const int* __restrict__ cmat,
                                                  int* __restrict__ P) {
    int is64 = detect_is64(src32);
    __shared__ int cur[NBUCK];
    int t = threadIdx.x, blk = blockIdx.x;
    for (int i = t; i < NBUCK; i += 256) cur[i] = cmat[i * NBLKA + blk];
    __syncthreads();
    int e0 = blk * EPB, e1 = e0 + EPB; if (e1 > N_EDGES) e1 = N_EDGES;
    for (int e = e0 + t; e < e1; e += 256) {
        unsigned d = load_idx(dst32, dst64, is64, e);
        if (d < N_NODES) {
            unsigned s = load_idx(src32, src64, is64, e);
            int pos = atomicAdd(&cur[d >> 8], 1);
            P[pos] = (int)(((d & 255u) << 17) | (s & 0x1FFFFu));
        }
    }
}

// B: per-bucket counting sort -> adj, rowstart, rowend, dinv
__global__ __launch_bounds__(256) void k_bbuild(const int* __restrict__ P,
                                                const int* __restrict__ bt,
                                                int* __restrict__ adj,
                                                int* __restrict__ rowstart,
                                                int* __restrict__ rowend,
                                                float* __restrict__ dinv) {
    __shared__ int cnt[NPB];
    __shared__ int s[NPB];
    int b = blockIdx.x, t = threadIdx.x;
    int bo = bt[b], be = bt[b + 1];
    cnt[t] = 0;
    __syncthreads();
    for (int i = bo + t; i < be; i += 256)
        atomicAdd(&cnt[__builtin_nontemporal_load(&P[i]) >> 17], 1);
    __syncthreads();
    s[t] = cnt[t];
    __syncthreads();
    for (int off = 1; off < 256; off <<= 1) {
        int v = (t >= off) ? s[t - off] : 0;
        __syncthreads();
        s[t] += v;
        __syncthreads();
    }
    int ex = (t == 0) ? 0 : s[t - 1];
    int node = b * NPB + t;
    if (node < N_NODES) {
        rowstart[node] = bo + ex;
        rowend[node]   = bo + ex + cnt[t];
        dinv[node]     = rsqrtf((float)cnt[t] + 1.0f);
    }
    __syncthreads();
    s[t] = ex;  // cursors
    __syncthreads();
    for (int i = bo + t; i < be; i += 256) {
        int ent = __builtin_nontemporal_load(&P[i]);
        int pos = bo + atomicAdd(&s[ent >> 17], 1);
        adj[pos] = ent & 0x1FFFF;
    }
}

// ---------------------------------------------------------------------------
// Layer-1 GEMM -> two 8-float planes: xs[p][n][f] = dinv[n]*(h@W1)[n][p*8+f]
__global__ __launch_bounds__(256) void k_gemm1_p(const float* __restrict__ h,
                                                 const float* __restrict__ W,
                                                 const float* __restrict__ dinv,
                                                 float* __restrict__ xs) {
    __shared__ float Wt[16 * 132];
    __shared__ float Hs[16 * 132];
    int tid = threadIdx.x;
    for (int i = tid; i < 2048; i += 256) {
        int k = i >> 4, f = i & 15;
        Wt[f * 132 + k] = W[i];
    }
    int nodeBase = blockIdx.x * 16;
    for (int i = tid; i < 512; i += 256) {
        int r = i >> 5, c = i & 31;
        f4nt v = __builtin_nontemporal_load(
            ((const f4nt*)(h + (size_t)(nodeBase + r) * 128)) + c);
        *((f4nt*)&Hs[r * 132 + c * 4]) = v;
    }
    __syncthreads();
    int nl = tid >> 4, f = tid & 15;
    int n = nodeBase + nl;
    const float* hr = &Hs[nl * 132];
    const float* wr = &Wt[f * 132];
    float s = 0.0f;
#pragma unroll
    for (int k = 0; k < 128; k++) s += hr[k] * wr[k];
    s *= dinv[n];
    xs[(f >> 3) * (8 * N_NODES) + n * 8 + (f & 7)] = s;
}

// small GEMM -> FO-wide plane (pre-scaled by dinv)
template <int FI, int FO>
__global__ __launch_bounds__(256) void k_gemm_smallp(const float* __restrict__ x,
                                                     const float* __restrict__ W,
                                                     const float* __restrict__ dinv,
                                                     float* __restrict__ xs) {
    int i = blockIdx.x * 256 + threadIdx.x;
    if (i >= N_NODES * FO) return;
    int n = i / FO, f = i % FO;
    float s = 0.0f;
#pragma unroll
    for (int k = 0; k < FI; k++) s += x[n * FI + k] * W[k * FO + f];
    xs[i] = s * dinv[n];
}

// ---------------------------------------------------------------------------
// Layer-1 dual-plane pull: one wave per node, 8 slots x 8 features.
// Per edge: one adj load (prefetched) + two independent 32B gathers.
__global__ __launch_bounds__(256) void k_pull16_dual(const float* __restrict__ p0,
                                                     const float* __restrict__ p1,
                                                     const int* __restrict__ adj,
                                                     const int* __restrict__ rowstart,
                                                     const int* __restrict__ rowend,
                                                     const float* __restrict__ dinv,
                                                     const float* __restrict__ b1,
                                                     float* __restrict__ out) {
    int t = threadIdx.x;
    int g = t >> 6;              // wave in block = node
    int q = t & 63;
    int f = q & 7, k = q >> 3;   // feature, slot (R=8)
    int n = blockIdx.x * 4 + g;
    if (n >= N_NODES) return;
    int s0 = rowstart[n], e0 = rowend[n];
    float a0 = 0.0f, a1 = 0.0f;
    int j = s0 + k;
    if (j < e0) {
        int src = __builtin_nontemporal_load(&adj[j]);
        while (true) {
            int jn = j + 8;
            bool more = jn < e0;
            int srcn = 0;
            if (more) srcn = __builtin_nontemporal_load(&adj[jn]);  // prefetch
            a0 += p0[src * 8 + f];
            a1 += p1[src * 8 + f];
            if (!more) break;
            j = jn; src = srcn;
        }
    }
#pragma unroll
    for (int off = 32; off >= 8; off >>= 1) {
        a0 += __shfl_xor(a0, off, 64);
        a1 += __shfl_xor(a1, off, 64);
    }
    if (k == 0) {
        a0 += p0[n * 8 + f];     // self loop
        a1 += p1[n * 8 + f];
        float di = dinv[n];
        out[n * 16 + f]     = tanhf(di * a0 + b1[f]);
        out[n * 16 + 8 + f] = tanhf(di * a1 + b1[8 + f]);
    }
}

// Generic CSR pull + fused finish (layer 2). NL lanes/node, R=NL/F slots.
template <int F, int NL, int FTOT, int FOFF>
__global__ __launch_bounds__(256) void k_pull(const float* __restrict__ xsp,
                                              const int* __restrict__ adj,
                                              const int* __restrict__ rowstart,
                                              const int* __restrict__ rowend,
                                              const float* __restrict__ dinv,
                                              const float* __restrict__ bias,
                                              float* __restrict__ out) {
    constexpr int R = NL / F;
    int t = threadIdx.x;
    int g = t / NL, q = t % NL;
    int f = q % F, k = q / F;
    int n = blockIdx.x * (256 / NL) + g;
    if (n >= N_NODES) return;
    int s0 = rowstart[n], e0 = rowend[n];
    float acc = 0.0f;
    int j = s0 + k;
    if (j < e0) {
        int src = __builtin_nontemporal_load(&adj[j]);
        while (true) {
            int jn = j + R;
            bool more = jn < e0;
            int srcn = 0;
            if (more) srcn = __builtin_nontemporal_load(&adj[jn]);  // prefetch
            acc += xsp[src * F + f];
            if (!more) break;
            j = jn; src = srcn;
        }
    }
#pragma unroll
    for (int off = NL / 2; off >= F; off >>= 1)
        acc += __shfl_xor(acc, off, 64);
    if (k == 0) {
        acc += xsp[n * F + f];  // self loop
        out[n * FTOT + FOFF + f] = tanhf(dinv[n] * acc + bias[f]);
    }
}

// Layer-3 pull (F=2, NL=8, R=4) fused with h3 write and 2->8 classifier.
__global__ __launch_bounds__(256) void k_pull_final(const float* __restrict__ xsp,
                                                    const int* __restrict__ adj,
                                                    const int* __restrict__ rowstart,
                                                    const int* __restrict__ rowend,
                                                    const float* __restrict__ dinv,
                                                    const float* __restrict__ b3,
                                                    const float* __restrict__ Wc,
                                                    const float* __restrict__ bc,
                                                    float* __restrict__ out,
                                                    float* __restrict__ h3out) {
    const int NL = 8;
    int t = threadIdx.x;
    int g = t / NL, q = t % NL;
    int f = q & 1, k = q >> 1;
    int n = blockIdx.x * (256 / NL) + g;
    if (n >= N_NODES) return;
    int s0 = rowstart[n], e0 = rowend[n];
    float acc = 0.0f;
    int j = s0 + k;
    if (j < e0) {
        int src = __builtin_nontemporal_load(&adj[j]);
        while (true) {
            int jn = j + 4;
            bool more = jn < e0;
            int srcn = 0;
            if (more) srcn = __builtin_nontemporal_load(&adj[jn]);
            acc += xsp[src * 2 + f];
            if (!more) break;
            j = jn; src = srcn;
        }
    }
    acc += __shfl_xor(acc, 4, 64);
    acc += __shfl_xor(acc, 2, 64);
    float a = 0.0f;
    if (q < 2) {
        acc += xsp[n * 2 + f];
        a = tanhf(dinv[n] * acc + b3[f]);
        h3out[2 * n + f] = a;
    }
    int wl = t & 63, gb = wl & ~7;
    float a0 = __shfl(a, gb, 64);
    float a1 = __shfl(a, gb + 1, 64);
    out[8 * n + q] = a0 * Wc[q] + a1 * Wc[8 + q] + bc[q];
}

// ---------------------------------------------------------------------------
// Atomic fallback (R4 pipeline) — only if ws is unexpectedly small
__global__ __launch_bounds__(256) void k_gemm1(const float* __restrict__ h,
                                               const float* __restrict__ W,
                                               const float* __restrict__ dinv,
                                               float* __restrict__ xs, float* acc) {
    __shared__ float Wt[16 * 132];
    __shared__ float Hs[16 * 132];
    int tid = threadIdx.x;
    for (int i = tid; i < 2048; i += 256) {
        int k = i >> 4, f = i & 15;
        Wt[f * 132 + k] = W[i];
    }
    int nodeBase = blockIdx.x * 16;
    for (int i = tid; i < 512; i += 256) {
        int r = i >> 5, c = i & 31;
        float4 v = ((const float4*)(h + (size_t)(nodeBase + r) * 128))[c];
        *((float4*)&Hs[r * 132 + c * 4]) = v;
    }
    __syncthreads();
    int nl = tid >> 4, f = tid & 15;
    int n = nodeBase + nl;
    const float* hr = &Hs[nl * 132];
    const float* wr = &Wt[f * 132];
    float s = 0.0f;
#pragma unroll
    for (int k = 0; k < 128; k++) s += hr[k] * wr[k];
    s *= dinv[n];
    xs[n * 16 + f] = s;
    acc[n * 16 + f] = s;
}
template <int FI, int FO>
__global__ __launch_bounds__(256) void k_gemm_small(const float* __restrict__ x,
                                                    const float* __restrict__ W,
                                                    const float* __restrict__ dinv,
                                                    float* __restrict__ xs, float* acc) {
    int i = blockIdx.x * 256 + threadIdx.x;
    if (i >= N_NODES * FO) return;
    int n = i / FO, f = i % FO;
    float s = 0.0f;
#pragma unroll
    for (int k = 0; k < FI; k++) s += x[n * FI + k] * W[k * FO + f];
    s *= dinv[n];
    xs[i] = s;
    acc[i] = s;
}
template <int F>
__global__ __launch_bounds__(256) void k_scatter(const int* __restrict__ src32,
                                                 const long long* __restrict__ src64,
                                                 const int* __restrict__ dst32,
                                                 const long long* __restrict__ dst64,
                                                 const int* __restrict__ flag,
                                                 const float* __restrict__ xs,
                                                 float* __restrict__ acc) {
    long long gid = (long long)blockIdx.x * 256 + threadIdx.x;
    int e = (int)(gid / F), f = (int)(gid % F);
    if (e < N_EDGES) {
        int is64 = *flag;
        unsigned s = load_idx(src32, src64, is64, e);
        unsigned d = load_idx(dst32, dst64, is64, e);
        if (s < N_NODES && d < N_NODES)
            atomicAdd(&acc[d * F + f], xs[s * F + f]);
    }
}
__global__ __launch_bounds__(256) void k_deg_init(float* __restrict__ deg) {
    int i = blockIdx.x * 256 + threadIdx.x;
    if (i < N_NODES) deg[i] = 1.0f;
}
__global__ __launch_bounds__(256) void k_deg_count(const int* __restrict__ dst32,
                                                   const long long* __restrict__ dst64,
                                                   const int* __restrict__ flag,
                                                   float* __restrict__ deg) {
    int e = blockIdx.x * 256 + threadIdx.x;
    if (e < N_EDGES) {
        unsigned d = load_idx(dst32, dst64, *flag, e);
        if (d < N_NODES) atomicAdd(&deg[d], 1.0f);
    }
}
__global__ __launch_bounds__(256) void k_rsqrt(float* __restrict__ deg) {
    int i = blockIdx.x * 256 + threadIdx.x;
    if (i < N_NODES) deg[i] = rsqrtf(deg[i]);
}
template <int F>
__global__ __launch_bounds__(256) void k_finish(const float* __restrict__ acc,
                                                const float* __restrict__ dinv,
                                                const float* __restrict__ b,
                                                float* __restrict__ out) {
    int i = blockIdx.x * 256 + threadIdx.x;
    if (i >= N_NODES * F) return;
    int n = i / F, f = i % F;
    out[i] = tanhf(dinv[n] * acc[i] + b[f]);
}
__global__ __launch_bounds__(256) void k_final(const float* __restrict__ acc3,
                                               const float* __restrict__ dinv,
                                               const float* __restrict__ b3,
                                               const float* __restrict__ Wc,
                                               const float* __restrict__ bc,
                                               float* __restrict__ out,
                                               float* __restrict__ h3out) {
    int n = blockIdx.x * 256 + threadIdx.x;
    if (n >= N_NODES) return;
    float di = dinv[n];
    float a0 = tanhf(di * acc3[2 * n + 0] + b3[0]);
    float a1 = tanhf(di * acc3[2 * n + 1] + b3[1]);
    h3out[2 * n + 0] = a0;
    h3out[2 * n + 1] = a1;
#pragma unroll
    for (int c = 0; c < 8; c++)
        out[8 * n + c] = a0 * Wc[c] + a1 * Wc[8 + c] + bc[c];
}
__global__ __launch_bounds__(256) void k_zero_out(float* __restrict__ out, int n) {
    int i = blockIdx.x * 256 + threadIdx.x;
    if (i < n) out[i] = 0.0f;
}

// ---------------------------------------------------------------------------
extern "C" void kernel_launch(void* const* d_in, const int* in_sizes, int n_in,
                              void* d_out, int out_size, void* d_ws, size_t ws_size,
                              hipStream_t stream) {
    float* out = (float*)d_out;
    const float* h   = (const float*)d_in[0];
    const void*  ei  = d_in[1];
    const float* W1  = (const float*)d_in[2];
    const float* b1  = (const float*)d_in[3];
    const float* W2  = (const float*)d_in[4];
    const float* b2  = (const float*)d_in[5];
    const float* W3  = (const float*)d_in[6];
    const float* b3  = (const float*)d_in[7];
    const float* Wc  = (const float*)d_in[8];
    const float* bc  = (const float*)d_in[9];

    const int*       src32 = (const int*)ei;
    const int*       dst32 = src32 + N_EDGES;
    const long long* src64 = (const long long*)ei;
    const long long* dst64 = src64 + N_EDGES;

    float* h3out = out + 8 * N_NODES;
    const int NB_E = (N_EDGES + 255) / 256;

    if (d_ws != nullptr && ws_size >= MAIN_WS_BYTES) {
        // ------------- multisplit CSR + plane-pull path -------------
        float* dinv   = (float*)d_ws;                // N
        int* rowstart = (int*)(dinv + N_NODES);      // N
        int* rowend   = rowstart + N_NODES;          // N
        int* adj      = rowend + N_NODES;            // E
        int* S        = adj + N_EDGES;               // max(32N, E)
        float* xs     = (float*)S;                   // 16N (after build)
        float* hbuf   = xs + 16 * N_NODES;           // 16N
        int* P        = S;                           // E (during build)
        int* cmat     = S + 3200000;                 // NBUCK*NBLKA
        int* bt       = cmat + NBUCK * NBLKA;        // NBUCK+1

        k_bcount<<<NBLKA, 256, 0, stream>>>(dst32, dst64, cmat);
        k_bsum<<<NBUCK, 256, 0, stream>>>(cmat, bt);
        k_btscan<<<1, 512, 0, stream>>>(bt);
        k_boffs<<<NBUCK, 512, 0, stream>>>(cmat, bt);
        k_bscatter<<<NBLKA, 256, 0, stream>>>(src32, src64, dst32, dst64, cmat, P);
        k_bbuild<<<NBUCK, 256, 0, stream>>>(P, bt, adj, rowstart, rowend, dinv);

        // layer 1: 128 -> 16 via two 8-wide planes, single dual-plane pull
        k_gemm1_p<<<N_NODES / 16, 256, 0, stream>>>(h, W1, dinv, xs);
        k_pull16_dual<<<25000, 256, 0, stream>>>(
            xs, xs + 8 * N_NODES, adj, rowstart, rowend, dinv, b1, hbuf);
        // layer 2: 16 -> 4
        k_gemm_smallp<16, 4><<<(N_NODES * 4 + 255) / 256, 256, 0, stream>>>(hbuf, W2, dinv, xs);
        k_pull<4, 32, 4, 0><<<12500, 256, 0, stream>>>(
            xs, adj, rowstart, rowend, dinv, b2, hbuf);
        // layer 3: 4 -> 2, fused classifier
        k_gemm_smallp<4, 2><<<(N_NODES * 2 + 255) / 256, 256, 0, stream>>>(hbuf, W3, dinv, xs);
        k_pull_final<<<3125, 256, 0, stream>>>(
            xs, adj, rowstart, rowend, dinv, b3, Wc, bc, out, h3out);
        return;
    }

    if (d_ws != nullptr && ws_size >= ATOMIC_WS_BYTES) {
        // ------------- atomic fallback (R4) -------------
        float* ws   = (float*)d_ws;
        float* dinv = ws;
        float* bufA = dinv + N_NODES;
        float* bufB = bufA + 16 * N_NODES;
        int*   flag = (int*)(bufB + 16 * N_NODES);
        float* xs1 = bufA, *acc1 = bufB, *h1 = bufA;
        float* xs2 = bufB, *acc2 = bufB + 4 * N_NODES, *h2 = bufA;
        float* xs3 = bufB, *acc3 = bufB + 2 * N_NODES;

        k_detect_i64<<<1, 64, 0, stream>>>(src32, flag);
        k_deg_init<<<NB_BLK, 256, 0, stream>>>(dinv);
        k_deg_count<<<NB_E, 256, 0, stream>>>(dst32, dst64, flag, dinv);
        k_rsqrt<<<NB_BLK, 256, 0, stream>>>(dinv);
        k_gemm1<<<N_NODES / 16, 256, 0, stream>>>(h, W1, dinv, xs1, acc1);
        k_scatter<16><<<(int)(((long long)N_EDGES * 16 + 255) / 256), 256, 0, stream>>>(
            src32, src64, dst32, dst64, flag, xs1, acc1);
        k_finish<16><<<(N_NODES * 16 + 255) / 256, 256, 0, stream>>>(acc1, dinv, b1, h1);
        k_gemm_small<16, 4><<<(N_NODES * 4 + 255) / 256, 256, 0, stream>>>(h1, W2, dinv, xs2, acc2);
        k_scatter<4><<<(int)(((long long)N_EDGES * 4 + 255) / 256), 256, 0, stream>>>(
            src32, src64, dst32, dst64, flag, xs2, acc2);
        k_finish<4><<<(N_NODES * 4 + 255) / 256, 256, 0, stream>>>(acc2, dinv, b2, h2);
        k_gemm_small<4, 2><<<(N_NODES * 2 + 255) / 256, 256, 0, stream>>>(h2, W3, dinv, xs3, acc3);
        k_scatter<2><<<(int)(((long long)N_EDGES * 2 + 255) / 256), 256, 0, stream>>>(
            src32, src64, dst32, dst64, flag, xs3, acc3);
        k_final<<<NB_BLK, 256, 0, stream>>>(acc3, dinv, b3, Wc, bc, out, h3out);
        return;
    }

    k_zero_out<<<(out_size + 255) / 256, 256, 0, stream>>>(out, out_size);
}

// Round 12
// 365.781 us; speedup vs baseline: 2.0191x; 1.0612x over previous
//
#include <hip/hip_runtime.h>
#include <math.h>

#define N_NODES 100000
#define N_EDGES 3200000
#define NPB    256                               // nodes per bucket
#define NBUCK  ((N_NODES + NPB - 1) / NPB)       // 391
#define NBLKA  256                               // pass-A edge blocks (R6 config)
#define EPB    ((N_EDGES + NBLKA - 1) / NBLKA)   // 12500
#define NB_BLK ((N_NODES + 255) / 256)

// clang ext-vector for nontemporal float4 loads (HIP float4 is a struct and
// is rejected by __builtin_nontemporal_load)
typedef float f4nt __attribute__((ext_vector_type(4)));

// ws words: dinv N + rowstart N + rowend N + adj E + S max(32N,E)
//           + cmat NBUCK*NBLKA + bt (NBUCK+1) + flag
#define MAIN_WS_WORDS (3u*N_NODES + N_EDGES + 3200000u + NBUCK*NBLKA + NBUCK + 2u)
#define MAIN_WS_BYTES (MAIN_WS_WORDS * 4u)
#define ATOMIC_WS_BYTES ((33u*N_NODES + 16u) * 4u)

// ---------------------------------------------------------------------------
// per-wave edge-dtype probe on the START of ei: int64 LE values < 1e5 have all
// odd words zero. All 64 lanes of each wave must be active.
__device__ __forceinline__ int detect_is64(const int* __restrict__ ei_base) {
    int t = threadIdx.x & 63;
    int v = ei_base[2 * t + 1];
    unsigned long long nz = __ballot(v != 0);
    return nz == 0ull;
}

__global__ void k_detect_i64(const int* __restrict__ ei_words, int* __restrict__ flag) {
    if (blockIdx.x == 0 && threadIdx.x == 0) {
        int allzero = 1;
        for (int i = 0; i < 64; i++)
            if (ei_words[2 * i + 1] != 0) allzero = 0;
        *flag = allzero;  // 1 => int64 layout
    }
}

__device__ __forceinline__ unsigned load_idx(const int* p32, const long long* p64,
                                             int is64, int e) {
    return is64 ? (unsigned)(unsigned long long)__builtin_nontemporal_load(&p64[e])
                : (unsigned)__builtin_nontemporal_load(&p32[e]);
}

// ---------------------------------------------------------------------------
// A1: per-(bucket, edge-block) counts
__global__ __launch_bounds__(256) void k_bcount(const int* __restrict__ src32,
                                                const long long* __restrict__ dst64,
                                                int* __restrict__ cmat) {
    int is64 = detect_is64(src32);               // probe start of ei (in-bounds)
    const int* dst32 = src32 + N_EDGES;
    __shared__ int lc[NBUCK];
    int t = threadIdx.x, blk = blockIdx.x;
    for (int i = t; i < NBUCK; i += 256) lc[i] = 0;
    __syncthreads();
    int e0 = blk * EPB, e1 = e0 + EPB; if (e1 > N_EDGES) e1 = N_EDGES;
    for (int e = e0 + t; e < e1; e += 256) {
        unsigned d = load_idx(dst32, dst64, is64, e);
        if (d < N_NODES) atomicAdd(&lc[d >> 8], 1);
    }
    __syncthreads();
    for (int b = t; b < NBUCK; b += 256) cmat[b * NBLKA + blk] = lc[b];
}

// A2: bucket totals (NBLKA=256)
__global__ __launch_bounds__(256) void k_bsum(const int* __restrict__ cmat,
                                              int* __restrict__ bt) {
    int b = blockIdx.x, t = threadIdx.x;
    int v = cmat[b * NBLKA + t];
#pragma unroll
    for (int off = 32; off > 0; off >>= 1) v += __shfl_down(v, off, 64);
    __shared__ int s[4];
    if ((t & 63) == 0) s[t >> 6] = v;
    __syncthreads();
    if (t == 0) bt[b] = s[0] + s[1] + s[2] + s[3];
}

// A3: exclusive scan of bt[0..NBUCK); bt[NBUCK] = total
__global__ __launch_bounds__(512) void k_btscan(int* __restrict__ bt) {
    __shared__ int s[512];
    int t = threadIdx.x;
    s[t] = (t < NBUCK) ? bt[t] : 0;
    __syncthreads();
    for (int off = 1; off < 512; off <<= 1) {
        int v = (t >= off) ? s[t - off] : 0;
        __syncthreads();
        s[t] += v;
        __syncthreads();
    }
    if (t < NBUCK) bt[t] = (t == 0) ? 0 : s[t - 1];
    if (t == 0) bt[NBUCK] = s[NBUCK - 1];
}

// A4: cmat row -> absolute offsets
__global__ __launch_bounds__(256) void k_boffs(int* __restrict__ cmat,
                                               const int* __restrict__ bt) {
    __shared__ int s[256];
    int b = blockIdx.x, t = threadIdx.x;
    s[t] = cmat[b * NBLKA + t];
    __syncthreads();
    for (int off = 1; off < 256; off <<= 1) {
        int v = (t >= off) ? s[t - off] : 0;
        __syncthreads();
        s[t] += v;
        __syncthreads();
    }
    cmat[b * NBLKA + t] = ((t == 0) ? 0 : s[t - 1]) + bt[b];
}

// A5: scatter packed (dstLow<<17 | src) into bucket-major P
__global__ __launch_bounds__(256) void k_bscatter(const int* __restrict__ src32,
                                                  const long long* __restrict__ src64,
                                                  const long long* __restrict__ dst64,
                                                  const int* __restrict__ cmat,
                                                  int* __restrict__ P) {
    int is64 = detect_is64(src32);
    const int* dst32 = src32 + N_EDGES;
    __shared__ int cur[NBUCK];
    int t = threadIdx.x, blk = blockIdx.x;
    for (int i = t; i < NBUCK; i += 256) cur[i] = cmat[i * NBLKA + blk];
    __syncthreads();
    int e0 = blk * EPB, e1 = e0 + EPB; if (e1 > N_EDGES) e1 = N_EDGES;
    for (int e = e0 + t; e < e1; e += 256) {
        unsigned d = load_idx(dst32, dst64, is64, e);
        if (d < N_NODES) {
            unsigned s = load_idx(src32, src64, is64, e);
            int pos = atomicAdd(&cur[d >> 8], 1);
            P[pos] = (int)(((d & 255u) << 17) | (s & 0x1FFFFu));
        }
    }
}

// B: per-bucket counting sort -> adj, rowstart, rowend, dinv
__global__ __launch_bounds__(256) void k_bbuild(const int* __restrict__ P,
                                                const int* __restrict__ bt,
                                                int* __restrict__ adj,
                                                int* __restrict__ rowstart,
                                                int* __restrict__ rowend,
                                                float* __restrict__ dinv) {
    __shared__ int cnt[NPB];
    __shared__ int s[NPB];
    int b = blockIdx.x, t = threadIdx.x;
    int bo = bt[b], be = bt[b + 1];
    cnt[t] = 0;
    __syncthreads();
    for (int i = bo + t; i < be; i += 256)
        atomicAdd(&cnt[__builtin_nontemporal_load(&P[i]) >> 17], 1);
    __syncthreads();
    s[t] = cnt[t];
    __syncthreads();
    for (int off = 1; off < 256; off <<= 1) {
        int v = (t >= off) ? s[t - off] : 0;
        __syncthreads();
        s[t] += v;
        __syncthreads();
    }
    int ex = (t == 0) ? 0 : s[t - 1];
    int node = b * NPB + t;
    if (node < N_NODES) {
        rowstart[node] = bo + ex;
        rowend[node]   = bo + ex + cnt[t];
        dinv[node]     = rsqrtf((float)cnt[t] + 1.0f);
    }
    __syncthreads();
    s[t] = ex;  // cursors
    __syncthreads();
    for (int i = bo + t; i < be; i += 256) {
        int ent = __builtin_nontemporal_load(&P[i]);
        int pos = bo + atomicAdd(&s[ent >> 17], 1);
        adj[pos] = ent & 0x1FFFF;
    }
}

// ---------------------------------------------------------------------------
// Layer-1 GEMM -> two 8-float planes: xs[p][n][f] = dinv[n]*(h@W1)[n][p*8+f]
__global__ __launch_bounds__(256) void k_gemm1_p(const float* __restrict__ h,
                                                 const float* __restrict__ W,
                                                 const float* __restrict__ dinv,
                                                 float* __restrict__ xs) {
    __shared__ float Wt[16 * 132];
    __shared__ float Hs[16 * 132];
    int tid = threadIdx.x;
    for (int i = tid; i < 2048; i += 256) {
        int k = i >> 4, f = i & 15;
        Wt[f * 132 + k] = W[i];
    }
    int nodeBase = blockIdx.x * 16;
    for (int i = tid; i < 512; i += 256) {
        int r = i >> 5, c = i & 31;
        f4nt v = __builtin_nontemporal_load(
            ((const f4nt*)(h + (size_t)(nodeBase + r) * 128)) + c);
        *((f4nt*)&Hs[r * 132 + c * 4]) = v;
    }
    __syncthreads();
    int nl = tid >> 4, f = tid & 15;
    int n = nodeBase + nl;
    const float* hr = &Hs[nl * 132];
    const float* wr = &Wt[f * 132];
    float s = 0.0f;
#pragma unroll
    for (int k = 0; k < 128; k++) s += hr[k] * wr[k];
    s *= dinv[n];
    xs[(f >> 3) * (8 * N_NODES) + n * 8 + (f & 7)] = s;
}

// small GEMM -> FO-wide plane (pre-scaled by dinv)
template <int FI, int FO>
__global__ __launch_bounds__(256) void k_gemm_smallp(const float* __restrict__ x,
                                                     const float* __restrict__ W,
                                                     const float* __restrict__ dinv,
                                                     float* __restrict__ xs) {
    int i = blockIdx.x * 256 + threadIdx.x;
    if (i >= N_NODES * FO) return;
    int n = i / FO, f = i % FO;
    float s = 0.0f;
#pragma unroll
    for (int k = 0; k < FI; k++) s += x[n * FI + k] * W[k * FO + f];
    xs[i] = s * dinv[n];
}

// ---------------------------------------------------------------------------
// Layer-1 dual-plane pull: one wave per node, 8 slots x 8 features.
// Per edge: one adj load (prefetched, cached) + two independent 32B gathers.
__global__ __launch_bounds__(256) void k_pull16_dual(const float* __restrict__ p0,
                                                     const float* __restrict__ p1,
                                                     const int* __restrict__ adj,
                                                     const int* __restrict__ rowstart,
                                                     const int* __restrict__ rowend,
                                                     const float* __restrict__ dinv,
                                                     const float* __restrict__ b1,
                                                     float* __restrict__ out) {
    int t = threadIdx.x;
    int g = t >> 6;              // wave in block = node
    int q = t & 63;
    int f = q & 7, k = q >> 3;   // feature, slot (R=8)
    int n = blockIdx.x * 4 + g;
    if (n >= N_NODES) return;
    int s0 = rowstart[n], e0 = rowend[n];
    float a0 = 0.0f, a1 = 0.0f;
    int j = s0 + k;
    if (j < e0) {
        int src = adj[j];
        while (true) {
            int jn = j + 8;
            bool more = jn < e0;
            int srcn = 0;
            if (more) srcn = adj[jn];  // prefetch next index
            a0 += p0[src * 8 + f];
            a1 += p1[src * 8 + f];
            if (!more) break;
            j = jn; src = srcn;
        }
    }
#pragma unroll
    for (int off = 32; off >= 8; off >>= 1) {
        a0 += __shfl_xor(a0, off, 64);
        a1 += __shfl_xor(a1, off, 64);
    }
    if (k == 0) {
        a0 += p0[n * 8 + f];     // self loop
        a1 += p1[n * 8 + f];
        float di = dinv[n];
        out[n * 16 + f]     = tanhf(di * a0 + b1[f]);
        out[n * 16 + 8 + f] = tanhf(di * a1 + b1[8 + f]);
    }
}

// Generic CSR pull + fused finish (layer 2). NL lanes/node, R=NL/F slots.
template <int F, int NL, int FTOT, int FOFF>
__global__ __launch_bounds__(256) void k_pull(const float* __restrict__ xsp,
                                              const int* __restrict__ adj,
                                              const int* __restrict__ rowstart,
                                              const int* __restrict__ rowend,
                                              const float* __restrict__ dinv,
                                              const float* __restrict__ bias,
                                              float* __restrict__ out) {
    constexpr int R = NL / F;
    int t = threadIdx.x;
    int g = t / NL, q = t % NL;
    int f = q % F, k = q / F;
    int n = blockIdx.x * (256 / NL) + g;
    if (n >= N_NODES) return;
    int s0 = rowstart[n], e0 = rowend[n];
    float acc = 0.0f;
    int j = s0 + k;
    if (j < e0) {
        int src = adj[j];
        while (true) {
            int jn = j + R;
            bool more = jn < e0;
            int srcn = 0;
            if (more) srcn = adj[jn];
            acc += xsp[src * F + f];
            if (!more) break;
            j = jn; src = srcn;
        }
    }
#pragma unroll
    for (int off = NL / 2; off >= F; off >>= 1)
        acc += __shfl_xor(acc, off, 64);
    if (k == 0) {
        acc += xsp[n * F + f];  // self loop
        out[n * FTOT + FOFF + f] = tanhf(dinv[n] * acc + bias[f]);
    }
}

// Layer-3 pull (F=2, NL=8, R=4) fused with h3 write and 2->8 classifier.
__global__ __launch_bounds__(256) void k_pull_final(const float* __restrict__ xsp,
                                                    const int* __restrict__ adj,
                                                    const int* __restrict__ rowstart,
                                                    const int* __restrict__ rowend,
                                                    const float* __restrict__ dinv,
                                                    const float* __restrict__ b3,
                                                    const float* __restrict__ Wc,
                                                    const float* __restrict__ bc,
                                                    float* __restrict__ out,
                                                    float* __restrict__ h3out) {
    const int NL = 8;
    int t = threadIdx.x;
    int g = t / NL, q = t % NL;
    int f = q & 1, k = q >> 1;
    int n = blockIdx.x * (256 / NL) + g;
    if (n >= N_NODES) return;
    int s0 = rowstart[n], e0 = rowend[n];
    float acc = 0.0f;
    int j = s0 + k;
    if (j < e0) {
        int src = adj[j];
        while (true) {
            int jn = j + 4;
            bool more = jn < e0;
            int srcn = 0;
            if (more) srcn = adj[jn];
            acc += xsp[src * 2 + f];
            if (!more) break;
            j = jn; src = srcn;
        }
    }
    acc += __shfl_xor(acc, 4, 64);
    acc += __shfl_xor(acc, 2, 64);
    float a = 0.0f;
    if (q < 2) {
        acc += xsp[n * 2 + f];
        a = tanhf(dinv[n] * acc + b3[f]);
        h3out[2 * n + f] = a;
    }
    int wl = t & 63, gb = wl & ~7;
    float a0 = __shfl(a, gb, 64);
    float a1 = __shfl(a, gb + 1, 64);
    out[8 * n + q] = a0 * Wc[q] + a1 * Wc[8 + q] + bc[q];
}

// ---------------------------------------------------------------------------
// Atomic fallback (R4 pipeline) — only if ws is unexpectedly small
__global__ __launch_bounds__(256) void k_gemm1(const float* __restrict__ h,
                                               const float* __restrict__ W,
                                               const float* __restrict__ dinv,
                                               float* __restrict__ xs, float* acc) {
    __shared__ float Wt[16 * 132];
    __shared__ float Hs[16 * 132];
    int tid = threadIdx.x;
    for (int i = tid; i < 2048; i += 256) {
        int k = i >> 4, f = i & 15;
        Wt[f * 132 + k] = W[i];
    }
    int nodeBase = blockIdx.x * 16;
    for (int i = tid; i < 512; i += 256) {
        int r = i >> 5, c = i & 31;
        float4 v = ((const float4*)(h + (size_t)(nodeBase + r) * 128))[c];
        *((float4*)&Hs[r * 132 + c * 4]) = v;
    }
    __syncthreads();
    int nl = tid >> 4, f = tid & 15;
    int n = nodeBase + nl;
    const float* hr = &Hs[nl * 132];
    const float* wr = &Wt[f * 132];
    float s = 0.0f;
#pragma unroll
    for (int k = 0; k < 128; k++) s += hr[k] * wr[k];
    s *= dinv[n];
    xs[n * 16 + f] = s;
    acc[n * 16 + f] = s;
}
template <int FI, int FO>
__global__ __launch_bounds__(256) void k_gemm_small(const float* __restrict__ x,
                                                    const float* __restrict__ W,
                                                    const float* __restrict__ dinv,
                                                    float* __restrict__ xs, float* acc) {
    int i = blockIdx.x * 256 + threadIdx.x;
    if (i >= N_NODES * FO) return;
    int n = i / FO, f = i % FO;
    float s = 0.0f;
#pragma unroll
    for (int k = 0; k < FI; k++) s += x[n * FI + k] * W[k * FO + f];
    s *= dinv[n];
    xs[i] = s;
    acc[i] = s;
}
template <int F>
__global__ __launch_bounds__(256) void k_scatter(const int* __restrict__ src32,
                                                 const long long* __restrict__ src64,
                                                 const int* __restrict__ dst32,
                                                 const long long* __restrict__ dst64,
                                                 const int* __restrict__ flag,
                                                 const float* __restrict__ xs,
                                                 float* __restrict__ acc) {
    long long gid = (long long)blockIdx.x * 256 + threadIdx.x;
    int e = (int)(gid / F), f = (int)(gid % F);
    if (e < N_EDGES) {
        int is64 = *flag;
        unsigned s = load_idx(src32, src64, is64, e);
        unsigned d = load_idx(dst32, dst64, is64, e);
        if (s < N_NODES && d < N_NODES)
            atomicAdd(&acc[d * F + f], xs[s * F + f]);
    }
}
__global__ __launch_bounds__(256) void k_deg_init(float* __restrict__ deg) {
    int i = blockIdx.x * 256 + threadIdx.x;
    if (i < N_NODES) deg[i] = 1.0f;
}
__global__ __launch_bounds__(256) void k_deg_count(const int* __restrict__ dst32,
                                                   const long long* __restrict__ dst64,
                                                   const int* __restrict__ flag,
                                                   float* __restrict__ deg) {
    int e = blockIdx.x * 256 + threadIdx.x;
    if (e < N_EDGES) {
        unsigned d = load_idx(dst32, dst64, *flag, e);
        if (d < N_NODES) atomicAdd(&deg[d], 1.0f);
    }
}
__global__ __launch_bounds__(256) void k_rsqrt(float* __restrict__ deg) {
    int i = blockIdx.x * 256 + threadIdx.x;
    if (i < N_NODES) deg[i] = rsqrtf(deg[i]);
}
template <int F>
__global__ __launch_bounds__(256) void k_finish(const float* __restrict__ acc,
                                                const float* __restrict__ dinv,
                                                const float* __restrict__ b,
                                                float* __restrict__ out) {
    int i = blockIdx.x * 256 + threadIdx.x;
    if (i >= N_NODES * F) return;
    int n = i / F, f = i % F;
    out[i] = tanhf(dinv[n] * acc[i] + b[f]);
}
__global__ __launch_bounds__(256) void k_final(const float* __restrict__ acc3,
                                               const float* __restrict__ dinv,
                                               const float* __restrict__ b3,
                                               const float* __restrict__ Wc,
                                               const float* __restrict__ bc,
                                               float* __restrict__ out,
                                               float* __restrict__ h3out) {
    int n = blockIdx.x * 256 + threadIdx.x;
    if (n >= N_NODES) return;
    float di = dinv[n];
    float a0 = tanhf(di * acc3[2 * n + 0] + b3[0]);
    float a1 = tanhf(di * acc3[2 * n + 1] + b3[1]);
    h3out[2 * n + 0] = a0;
    h3out[2 * n + 1] = a1;
#pragma unroll
    for (int c = 0; c < 8; c++)
        out[8 * n + c] = a0 * Wc[c] + a1 * Wc[8 + c] + bc[c];
}
__global__ __launch_bounds__(256) void k_zero_out(float* __restrict__ out, int n) {
    int i = blockIdx.x * 256 + threadIdx.x;
    if (i < n) out[i] = 0.0f;
}

// ---------------------------------------------------------------------------
extern "C" void kernel_launch(void* const* d_in, const int* in_sizes, int n_in,
                              void* d_out, int out_size, void* d_ws, size_t ws_size,
                              hipStream_t stream) {
    float* out = (float*)d_out;
    const float* h   = (const float*)d_in[0];
    const void*  ei  = d_in[1];
    const float* W1  = (const float*)d_in[2];
    const float* b1  = (const float*)d_in[3];
    const float* W2  = (const float*)d_in[4];
    const float* b2  = (const float*)d_in[5];
    const float* W3  = (const float*)d_in[6];
    const float* b3  = (const float*)d_in[7];
    const float* Wc  = (const float*)d_in[8];
    const float* bc  = (const float*)d_in[9];

    const int*       src32 = (const int*)ei;
    const int*       dst32 = src32 + N_EDGES;
    const long long* src64 = (const long long*)ei;
    const long long* dst64 = src64 + N_EDGES;

    float* h3out = out + 8 * N_NODES;
    const int NB_E = (N_EDGES + 255) / 256;

    if (d_ws != nullptr && ws_size >= MAIN_WS_BYTES) {
        // ------------- multisplit CSR + dual-plane pull path -------------
        float* dinv   = (float*)d_ws;                // N
        int* rowstart = (int*)(dinv + N_NODES);      // N
        int* rowend   = rowstart + N_NODES;          // N
        int* adj      = rowend + N_NODES;            // E
        int* S        = adj + N_EDGES;               // max(32N, E)
        float* xs     = (float*)S;                   // 16N (after build)
        float* hbuf   = xs + 16 * N_NODES;           // 16N
        int* P        = S;                           // E (during build)
        int* cmat     = S + 3200000;                 // NBUCK*NBLKA
        int* bt       = cmat + NBUCK * NBLKA;        // NBUCK+1

        k_bcount<<<NBLKA, 256, 0, stream>>>(src32, dst64, cmat);
        k_bsum<<<NBUCK, 256, 0, stream>>>(cmat, bt);
        k_btscan<<<1, 512, 0, stream>>>(bt);
        k_boffs<<<NBUCK, 256, 0, stream>>>(cmat, bt);
        k_bscatter<<<NBLKA, 256, 0, stream>>>(src32, src64, dst64, cmat, P);
        k_bbuild<<<NBUCK, 256, 0, stream>>>(P, bt, adj, rowstart, rowend, dinv);

        // layer 1: 128 -> 16 via two 8-wide planes, single dual-plane pull
        k_gemm1_p<<<N_NODES / 16, 256, 0, stream>>>(h, W1, dinv, xs);
        k_pull16_dual<<<25000, 256, 0, stream>>>(
            xs, xs + 8 * N_NODES, adj, rowstart, rowend, dinv, b1, hbuf);
        // layer 2: 16 -> 4  (R6-validated shape: NL=16, 6250 blocks)
        k_gemm_smallp<16, 4><<<(N_NODES * 4 + 255) / 256, 256, 0, stream>>>(hbuf, W2, dinv, xs);
        k_pull<4, 16, 4, 0><<<6250, 256, 0, stream>>>(
            xs, adj, rowstart, rowend, dinv, b2, hbuf);
        // layer 3: 4 -> 2, fused classifier
        k_gemm_smallp<4, 2><<<(N_NODES * 2 + 255) / 256, 256, 0, stream>>>(hbuf, W3, dinv, xs);
        k_pull_final<<<3125, 256, 0, stream>>>(
            xs, adj, rowstart, rowend, dinv, b3, Wc, bc, out, h3out);
        return;
    }

    if (d_ws != nullptr && ws_size >= ATOMIC_WS_BYTES) {
        // ------------- atomic fallback (R4) -------------
        float* ws   = (float*)d_ws;
        float* dinv = ws;
        float* bufA = dinv + N_NODES;
        float* bufB = bufA + 16 * N_NODES;
        int*   flag = (int*)(bufB + 16 * N_NODES);
        float* xs1 = bufA, *acc1 = bufB, *h1 = bufA;
        float* xs2 = bufB, *acc2 = bufB + 4 * N_NODES, *h2 = bufA;
        float* xs3 = bufB, *acc3 = bufB + 2 * N_NODES;

        k_detect_i64<<<1, 64, 0, stream>>>(src32, flag);
        k_deg_init<<<NB_BLK, 256, 0, stream>>>(dinv);
        k_deg_count<<<NB_E, 256, 0, stream>>>(dst32, dst64, flag, dinv);
        k_rsqrt<<<NB_BLK, 256, 0, stream>>>(dinv);
        k_gemm1<<<N_NODES / 16, 256, 0, stream>>>(h, W1, dinv, xs1, acc1);
        k_scatter<16><<<(int)(((long long)N_EDGES * 16 + 255) / 256), 256, 0, stream>>>(
            src32, src64, dst32, dst64, flag, xs1, acc1);
        k_finish<16><<<(N_NODES * 16 + 255) / 256, 256, 0, stream>>>(acc1, dinv, b1, h1);
        k_gemm_small<16, 4><<<(N_NODES * 4 + 255) / 256, 256, 0, stream>>>(h1, W2, dinv, xs2, acc2);
        k_scatter<4><<<(int)(((long long)N_EDGES * 4 + 255) / 256), 256, 0, stream>>>(
            src32, src64, dst32, dst64, flag, xs2, acc2);
        k_finish<4><<<(N_NODES * 4 + 255) / 256, 256, 0, stream>>>(acc2, dinv, b2, h2);
        k_gemm_small<4, 2><<<(N_NODES * 2 + 255) / 256, 256, 0, stream>>>(h2, W3, dinv, xs3, acc3);
        k_scatter<2><<<(int)(((long long)N_EDGES * 2 + 255) / 256), 256, 0, stream>>>(
            src32, src64, dst32, dst64, flag, xs3, acc3);
        k_final<<<NB_BLK, 256, 0, stream>>>(acc3, dinv, b3, Wc, bc, out, h3out);
        return;
    }

    k_zero_out<<<(out_size + 255) / 256, 256, 0, stream>>>(out, out_size);
}